// Round 8
// baseline (350.652 us; speedup 1.0000x reference)
//
#include <hip/hip_runtime.h>

typedef unsigned short u16;
typedef unsigned int u32;
typedef short bh8 __attribute__((ext_vector_type(8)));   // 8 bf16 (A/B frag)
typedef float f4 __attribute__((ext_vector_type(4)));    // 4 f32 (C/D frag)
typedef float pf2 __attribute__((ext_vector_type(2)));   // packed f32 pair

__device__ __forceinline__ float bf2f(u16 h) { return __uint_as_float(((u32)h) << 16); }
__device__ __forceinline__ float bflo(u32 u) { return __uint_as_float(u << 16); }
__device__ __forceinline__ float bfhi(u32 u) { return __uint_as_float(u & 0xffff0000u); }
__device__ __forceinline__ u16 f2bf(float f) {
    u32 x = __float_as_uint(f);
    return (u16)((x + 0x7fffu + ((x >> 16) & 1u)) >> 16);  // RNE
}
__device__ __forceinline__ pf2 pkfma(pf2 a, pf2 b, pf2 c) {
    pf2 d;
    asm("v_pk_fma_f32 %0, %1, %2, %3" : "=v"(d) : "v"(a), "v"(b), "v"(c));
    return d;
}
__device__ __forceinline__ pf2 u2f2(u32 u) {
    pf2 r;
    r.x = bflo(u);
    r.y = bfhi(u);
    return r;
}
// 16-lane sum via DPP (VALU pipe, no LDS)
__device__ __forceinline__ float dpp_red16(float x) {
    int y;
    y = __builtin_amdgcn_update_dpp(0, __float_as_int(x), 0xB1, 0xF, 0xF, true);
    x += __int_as_float(y);
    y = __builtin_amdgcn_update_dpp(0, __float_as_int(x), 0x4E, 0xF, 0xF, true);
    x += __int_as_float(y);
    y = __builtin_amdgcn_update_dpp(0, __float_as_int(x), 0x141, 0xF, 0xF, true);
    x += __int_as_float(y);
    y = __builtin_amdgcn_update_dpp(0, __float_as_int(x), 0x140, 0xF, 0xF, true);
    x += __int_as_float(y);
    return x;
}

#define KSCL 0.12751744336457488f  // (1/sqrt(128)) * log2(e)

// ---------------- K0a: A_h = W_node @ Wk_r[h], B_h = W_node @ Wk_s[h] ----------------
__global__ void k0a_kernel(const float* __restrict__ Wn, const float* __restrict__ Wks,
                           const float* __restrict__ Wkr, float* __restrict__ A,
                           float* __restrict__ B) {
    int idx = blockIdx.x * 256 + threadIdx.x;  // 2*4*64*128 = 65536
    if (idx >= 65536) return;
    int which = idx >> 15;
    int rem = idx & 32767;
    int h = rem >> 13;
    int r = rem & 8191;
    int a = r >> 7, dp = r & 127;
    const float* W = which ? Wks : Wkr;
    float acc = 0.f;
    for (int d = 0; d < 128; ++d)
        acc += Wn[a * 128 + d] * W[(h * 128 + d) * 128 + dp];
    (which ? B : A)[(h * 64 + a) * 128 + dp] = acc;
}

// ---------------- K0a2 ---------------------------------------------------------------
__global__ void k0a2_kernel(const float* __restrict__ bn, const float* __restrict__ Wks,
                            const float* __restrict__ Wkr, const float* __restrict__ bks,
                            const float* __restrict__ bkr, float* __restrict__ ybs,
                            float* __restrict__ ybr) {
    int idx = blockIdx.x * 256 + threadIdx.x;  // 2*4*128 = 1024
    if (idx >= 1024) return;
    int which = idx >> 9;
    int rem = idx & 511;
    int h = rem >> 7, dp = rem & 127;
    const float* W = which ? Wks : Wkr;
    const float* b = which ? bks : bkr;
    float acc = b[h * 128 + dp];
    for (int d = 0; d < 128; ++d) acc += bn[d] * W[(h * 128 + d) * 128 + dp];
    (which ? ybs : ybr)[h * 128 + dp] = acc;
}

// ---------------- K0b: assemble Wfold [64 x 708] + biasrow[708] ----------------------
// cols: [0:128) x | [128:640) v(h,i) | [640:704) u k-major: 640+k*4+h | [704:708) c0_h
__global__ void k0b_kernel(const float* __restrict__ Wn, const float* __restrict__ bn,
                           const float* __restrict__ A, const float* __restrict__ B,
                           const float* __restrict__ ybr, const float* __restrict__ ybs,
                           const float* __restrict__ Wks, const float* __restrict__ Wedge,
                           const float* __restrict__ bks, const float* __restrict__ bedge,
                           float* __restrict__ Wfold, float* __restrict__ biasrow) {
    int idx = blockIdx.x * 256 + threadIdx.x;  // 65*708
    if (idx >= 65 * 708) return;
    int a = idx / 708, c = idx % 708;
    float val;
    if (c < 128) {
        val = (a < 64) ? Wn[a * 128 + c] : bn[c];
    } else if (c < 640) {
        int h = (c - 128) >> 7, i = (c - 128) & 127;
        const float* rv = (a < 64) ? &A[(h * 64 + a) * 128] : &ybr[h * 128];
        float s = 0.f;
        for (int d = 0; d < 128; ++d) s += rv[d] * Wks[(h * 128 + i) * 128 + d];
        val = s;
    } else if (c < 704) {
        int k = (c - 640) >> 2, h = (c - 640) & 3;
        const float* rv = (a < 64) ? &B[(h * 64 + a) * 128] : &ybs[h * 128];
        float s = 0.f;
        for (int d = 0; d < 128; ++d) s += rv[d] * Wedge[k * 128 + d];
        val = s;
    } else {
        int h = c - 704;
        const float* rv = (a < 64) ? &B[(h * 64 + a) * 128] : &ybs[h * 128];
        float s = 0.f;
        for (int d = 0; d < 128; ++d) s += rv[d] * bedge[d];
        val = s;
    }
    if (a < 64) Wfold[(size_t)a * 708 + c] = val;
    else biasrow[c] = val;
}

// ---------------- wconv: bf16 transposed copies of Wfold and W_out -------------------
__global__ void wconv_kernel(const float* __restrict__ Wfold, const float* __restrict__ Wout,
                             u16* __restrict__ WfT, u16* __restrict__ WoT) {
    int i = blockIdx.x * 256 + threadIdx.x;
    if (i < 768 * 64) {
        int c = i >> 6, k = i & 63;
        WfT[i] = f2bf(c < 708 ? Wfold[(size_t)k * 708 + c] : 0.f);
    }
    int j = i - 768 * 64;
    if (j >= 0 && j < 128 * 512) {
        int c = j >> 9, k = j & 511;
        WoT[j] = f2bf(Wout[(size_t)k * 128 + c]);
    }
}

// ---------------- G1 (MFMA): split tables Xc[N,128], V[N,512](pre-scaled), U[N,64],
//                  E0[N,4] = exp2(kscl*c0) ------------------------------------------
__global__ __launch_bounds__(256) void g1_kernel(const float* __restrict__ nodes,
                                                 const u16* __restrict__ WfT,
                                                 const float* __restrict__ biasrow,
                                                 u16* __restrict__ Xc, u16* __restrict__ V,
                                                 u16* __restrict__ U, float* __restrict__ E0,
                                                 int N) {
    __shared__ u16 Asm[64][72];
    __shared__ u16 Bsm[128][72];
    int t = threadIdx.x;
    int r0 = blockIdx.x * 64, c0 = blockIdx.y * 128;
    {
        int row = t >> 2, cb = (t & 3) * 16;
        int r = r0 + row;
        u16 pk[16];
        if (r < N) {
            const float* src = &nodes[(size_t)r * 64 + cb];
#pragma unroll
            for (int q = 0; q < 16; ++q) pk[q] = f2bf(src[q]);
        } else {
#pragma unroll
            for (int q = 0; q < 16; ++q) pk[q] = 0;
        }
        *(uint4*)&Asm[row][cb] = *(const uint4*)&pk[0];
        *(uint4*)&Asm[row][cb + 8] = *(const uint4*)&pk[8];
    }
    {
        int col = t >> 1, ks = (t & 1) * 32;
        const u16* src = &WfT[(size_t)(c0 + col) * 64 + ks];
        uint4 v0 = *(const uint4*)src;
        uint4 v1 = *(const uint4*)(src + 8);
        uint4 v2 = *(const uint4*)(src + 16);
        uint4 v3 = *(const uint4*)(src + 24);
        *(uint4*)&Bsm[col][ks] = v0;
        *(uint4*)&Bsm[col][ks + 8] = v1;
        *(uint4*)&Bsm[col][ks + 16] = v2;
        *(uint4*)&Bsm[col][ks + 24] = v3;
    }
    __syncthreads();
    int lane = t & 63, wave = t >> 6;
    int wm = wave >> 1, wn = wave & 1;
    int lr = lane & 15, lk = lane >> 4;
    f4 acc[2][4] = {};
#pragma unroll
    for (int kk = 0; kk < 2; ++kk) {
        bh8 a[2], b[4];
#pragma unroll
        for (int am = 0; am < 2; ++am)
            a[am] = *(const bh8*)&Asm[wm * 32 + am * 16 + lr][kk * 32 + lk * 8];
#pragma unroll
        for (int bn = 0; bn < 4; ++bn)
            b[bn] = *(const bh8*)&Bsm[wn * 64 + bn * 16 + lr][kk * 32 + lk * 8];
#pragma unroll
        for (int am = 0; am < 2; ++am)
#pragma unroll
            for (int bn = 0; bn < 4; ++bn)
                acc[am][bn] = __builtin_amdgcn_mfma_f32_16x16x32_bf16(a[am], b[bn], acc[am][bn], 0, 0, 0);
    }
#pragma unroll
    for (int am = 0; am < 2; ++am)
#pragma unroll
        for (int bn = 0; bn < 4; ++bn) {
            int c = c0 + wn * 64 + bn * 16 + lr;
            if (c < 708) {
                float brow = biasrow[c];
#pragma unroll
                for (int q = 0; q < 4; ++q) {
                    int r = r0 + wm * 32 + am * 16 + lk * 4 + q;
                    if (r < N) {
                        float val = acc[am][bn][q] + brow;
                        if (c < 128) Xc[(size_t)r * 128 + c] = f2bf(val);
                        else if (c < 640) V[(size_t)r * 512 + (c - 128)] = f2bf(val * KSCL);
                        else if (c < 704) U[(size_t)r * 64 + (c - 640)] = f2bf(val * KSCL);
                        else E0[(size_t)r * 4 + (c - 704)] = exp2f(val * KSCL);
                    }
                }
            }
        }
}

// ---------------- CSR build ----------------------------------------------------------
__global__ void hist_kernel(const int* __restrict__ recv, int* __restrict__ deg, int E) {
    int e = blockIdx.x * 256 + threadIdx.x;
    if (e < E) atomicAdd(&deg[recv[e]], 1);
}

__global__ __launch_bounds__(1024) void scan1_kernel(const int* __restrict__ deg,
                                                     int* __restrict__ pre,
                                                     int* __restrict__ bsum, int N) {
    __shared__ int sm[1024];
    int b = blockIdx.x, t = threadIdx.x;
    int i = b * 1024 + t;
    int v = (i < N) ? deg[i] : 0;
    sm[t] = v;
    __syncthreads();
    for (int off = 1; off < 1024; off <<= 1) {
        int u = (t >= off) ? sm[t - off] : 0;
        __syncthreads();
        sm[t] += u;
        __syncthreads();
    }
    if (i < N) pre[i] = sm[t] - v;
    if (t == 1023) bsum[b] = sm[1023];
}

__global__ void scan2_kernel(int* __restrict__ bsum, int* __restrict__ boff, int nb) {
    int t = threadIdx.x;  // 64 threads, nb <= 64
    int own = (t < nb) ? bsum[t] : 0;
    int v = own;
#pragma unroll
    for (int off = 1; off < 64; off <<= 1) {
        int u = __shfl_up(v, off);
        if (t >= off) v += u;
    }
    if (t < nb) boff[t] = v - own;
    if (t == 63) boff[64] = v;
}

__global__ void scan3_kernel(const int* __restrict__ pre, const int* __restrict__ boff,
                             int* __restrict__ row_start, int* __restrict__ cursor, int N) {
    int i = blockIdx.x * 1024 + threadIdx.x;
    if (i < N) {
        int rsv = pre[i] + boff[i >> 10];
        row_start[i] = rsv;
        cursor[i] = rsv;
    }
    if (i == N) row_start[N] = boff[64];
}

// scatter writes fused (edge, sender) pairs -> en reads both with ONE load
__global__ void scatter_kernel(const int* __restrict__ recv, const int* __restrict__ senders,
                               int* __restrict__ cursor, int2* __restrict__ esp, int E) {
    int e = blockIdx.x * 256 + threadIdx.x;
    if (e < E) {
        int s = senders[e];
        int p = atomicAdd(&cursor[recv[e]], 1);
        esp[p] = make_int2(e, s);
    }
}

// ---------------- EN v6: split tables (L2-resident gather), 8 edges/step, exp2 -------
// Wave = (node, head-pair). Lane = (g,k16). Step = 8 edges (2 sub-chunks of 4).
__global__ __launch_bounds__(256, 4) void en_kernel(const int* __restrict__ row_start,
                                                    const int2* __restrict__ esp,
                                                    const float* __restrict__ edges,
                                                    const u16* __restrict__ Xc,
                                                    const u16* __restrict__ V,
                                                    const u16* __restrict__ Uu,
                                                    const float* __restrict__ E0,
                                                    const float* __restrict__ W_edge,
                                                    const float* __restrict__ b_edge,
                                                    u16* __restrict__ agg, int N) {
    __shared__ float Wl[2048];  // swizzled: (k, ch=8*k16+2i+b) at k*128+32*i+2*k16+b
    int t = threadIdx.x;
    for (int i = t; i < 2048; i += 256) {
        int k = i >> 7, ch = i & 127;
        int pos = (k << 7) | ((((ch >> 1) & 3) << 5) | (((ch >> 3) & 15) << 1) | (ch & 1));
        Wl[pos] = W_edge[i];
    }
    __syncthreads();
    int lane = t & 63, wid = t >> 6;
    int g = lane >> 4, k16 = lane & 15;
    int hp = wid & 1;  // heads 2hp, 2hp+1
    int nw = blockIdx.x * 2 + (wid >> 1);
    int NW = gridDim.x * 2;

#define IDX8(ea, sa, eb, sb, s_)                                            \
    {                                                                       \
        int ev = 0, sv = 0;                                                 \
        if (lane < 8) {                                                     \
            int jj = (s_)*8 + lane;                                         \
            if (jj >= deg) jj = deg - 1;                                    \
            int2 pv = esp[rs + jj];                                         \
            ev = pv.x; sv = pv.y;                                           \
        }                                                                   \
        ea = __shfl(ev, g); sa = __shfl(sv, g);                             \
        eb = __shfl(ev, 4 + g); sb = __shfl(sv, 4 + g);                     \
    }

#define LOADP(Xq, Uq, Eq, Zq, eI, sI)                                       \
    {                                                                       \
        Xq = *(const uint4*)(Xc + (size_t)(sI)*128 + 8 * k16);              \
        Uq = *(const u32*)(Uu + (size_t)(sI)*64 + k16 * 4 + 2 * hp);        \
        Eq = edges[(size_t)(eI)*16 + k16];                                  \
        Zq = *(const float2*)(E0 + (size_t)(sI)*4 + 2 * hp);                \
    }

#define COMP(Xq, Uq, Eq, Zq, act)                                           \
    {                                                                       \
        pf2 X0 = u2f2(Xq.x), X1 = u2f2(Xq.y), X2 = u2f2(Xq.z), X3 = u2f2(Xq.w); \
        float uh0 = bflo(Uq), uh1 = bfhi(Uq);                               \
        pf2 p2 = {Eq * uh0, 0.f};                                           \
        p2 = pkfma(X0, v00, p2); p2 = pkfma(X1, v01, p2);                   \
        p2 = pkfma(X2, v02, p2); p2 = pkfma(X3, v03, p2);                   \
        float p = dpp_red16(p2.x + p2.y);                                   \
        float wh = (act) ? Zq.x * exp2f(p) : 0.f;                           \
        Ss0 += wh; aE0 = fmaf(wh, Eq, aE0);                                 \
        pf2 w2 = {wh, wh};                                                  \
        aX00 = pkfma(w2, X0, aX00); aX01 = pkfma(w2, X1, aX01);             \
        aX02 = pkfma(w2, X2, aX02); aX03 = pkfma(w2, X3, aX03);             \
        pf2 q2 = {Eq * uh1, 0.f};                                           \
        q2 = pkfma(X0, v10, q2); q2 = pkfma(X1, v11, q2);                   \
        q2 = pkfma(X2, v12, q2); q2 = pkfma(X3, v13, q2);                   \
        float q = dpp_red16(q2.x + q2.y);                                   \
        float wg = (act) ? Zq.y * exp2f(q) : 0.f;                           \
        Ss1 += wg; aE1 = fmaf(wg, Eq, aE1);                                 \
        pf2 g2 = {wg, wg};                                                  \
        aX10 = pkfma(g2, X0, aX10); aX11 = pkfma(g2, X1, aX11);             \
        aX12 = pkfma(g2, X2, aX12); aX13 = pkfma(g2, X3, aX13);             \
    }

    for (int n = nw; n < N; n += NW) {
        int rs = row_start[n];
        int deg = row_start[n + 1] - rs;
        const u16* Vr = V + (size_t)n * 512;
        pf2 v00, v01, v02, v03, v10, v11, v12, v13;
        {
            uint4 v = *(const uint4*)(Vr + (2 * hp) * 128 + 8 * k16);
            v00 = u2f2(v.x); v01 = u2f2(v.y); v02 = u2f2(v.z); v03 = u2f2(v.w);
            uint4 w = *(const uint4*)(Vr + (2 * hp + 1) * 128 + 8 * k16);
            v10 = u2f2(w.x); v11 = u2f2(w.y); v12 = u2f2(w.z); v13 = u2f2(w.w);
        }
        pf2 aX00 = {0.f, 0.f}, aX01 = {0.f, 0.f}, aX02 = {0.f, 0.f}, aX03 = {0.f, 0.f};
        pf2 aX10 = {0.f, 0.f}, aX11 = {0.f, 0.f}, aX12 = {0.f, 0.f}, aX13 = {0.f, 0.f};
        float Ss0 = 0.f, Ss1 = 0.f, aE0 = 0.f, aE1 = 0.f;

        if (deg > 0) {
            int nst = (deg + 7) >> 3;
            int eA0, sA0, eA1, sA1, eB0, sB0, eB1, sB1;
            IDX8(eA0, sA0, eA1, sA1, 0);
            uint4 xP0, xP1; u32 uP0, uP1; float eP0, eP1; float2 zP0, zP1;
            LOADP(xP0, uP0, eP0, zP0, eA0, sA0);
            LOADP(xP1, uP1, eP1, zP1, eA1, sA1);
            if (nst > 1) {
                IDX8(eB0, sB0, eB1, sB1, 1);
            } else {
                eB0 = eA0; sB0 = sA0; eB1 = eA1; sB1 = sA1;
            }
            for (int s = 0; s < nst; ++s) {
                uint4 xc0 = xP0, xc1 = xP1;
                u32 uc0 = uP0, uc1 = uP1;
                float ec0 = eP0, ec1 = eP1;
                float2 zc0 = zP0, zc1 = zP1;
                int base = s * 8;
                if (s + 1 < nst) {
                    LOADP(xP0, uP0, eP0, zP0, eB0, sB0);
                    LOADP(xP1, uP1, eP1, zP1, eB1, sB1);
                    if (s + 2 < nst) IDX8(eB0, sB0, eB1, sB1, s + 2);
                }
                COMP(xc0, uc0, ec0, zc0, base + g < deg);
                COMP(xc1, uc1, ec1, zc1, base + 4 + g < deg);
            }
        }
        // cross-group reduce (sum over the 4 edge-groups)
#pragma unroll
        for (int msk = 16; msk <= 32; msk <<= 1) {
            aX00.x += __shfl_xor(aX00.x, msk); aX00.y += __shfl_xor(aX00.y, msk);
            aX01.x += __shfl_xor(aX01.x, msk); aX01.y += __shfl_xor(aX01.y, msk);
            aX02.x += __shfl_xor(aX02.x, msk); aX02.y += __shfl_xor(aX02.y, msk);
            aX03.x += __shfl_xor(aX03.x, msk); aX03.y += __shfl_xor(aX03.y, msk);
            aX10.x += __shfl_xor(aX10.x, msk); aX10.y += __shfl_xor(aX10.y, msk);
            aX11.x += __shfl_xor(aX11.x, msk); aX11.y += __shfl_xor(aX11.y, msk);
            aX12.x += __shfl_xor(aX12.x, msk); aX12.y += __shfl_xor(aX12.y, msk);
            aX13.x += __shfl_xor(aX13.x, msk); aX13.y += __shfl_xor(aX13.y, msk);
            Ss0 += __shfl_xor(Ss0, msk); Ss1 += __shfl_xor(Ss1, msk);
            aE0 += __shfl_xor(aE0, msk); aE1 += __shfl_xor(aE1, msk);
        }
        // finalize: groups (0,1)->head lo over k halves, (2,3)->head hi
        int hsel = g >> 1;
        int kh = (g & 1) << 3;
        bool prim = (g & 1) == 0;
        pf2 z = {0.f, 0.f};
        pf2 axg0 = prim ? (hsel ? aX10 : aX00) : z;
        pf2 axg1 = prim ? (hsel ? aX11 : aX01) : z;
        pf2 axg2 = prim ? (hsel ? aX12 : aX02) : z;
        pf2 axg3 = prim ? (hsel ? aX13 : aX03) : z;
        float aEg = hsel ? aE1 : aE0;
        float Sg = hsel ? Ss1 : Ss0;
        const pf2* Wp = (const pf2*)Wl;
#pragma unroll
        for (int kk = 0; kk < 8; ++kk) {
            int k = kh + kk;
            float a = __shfl(aEg, (lane & 48) | k);
            pf2 a2 = {a, a};
            int base = (k << 6) + k16;
            axg0 = pkfma(a2, Wp[base], axg0);
            axg1 = pkfma(a2, Wp[base + 16], axg1);
            axg2 = pkfma(a2, Wp[base + 32], axg2);
            axg3 = pkfma(a2, Wp[base + 48], axg3);
        }
        axg0.x += __shfl_xor(axg0.x, 16); axg0.y += __shfl_xor(axg0.y, 16);
        axg1.x += __shfl_xor(axg1.x, 16); axg1.y += __shfl_xor(axg1.y, 16);
        axg2.x += __shfl_xor(axg2.x, 16); axg2.y += __shfl_xor(axg2.y, 16);
        axg3.x += __shfl_xor(axg3.x, 16); axg3.y += __shfl_xor(axg3.y, 16);
        if (prim) {
            float inv = (deg > 0 && Sg > 0.f) ? 1.f / Sg : 0.f;
            float bes = (deg > 0) ? 1.f : 0.f;
            const float* br = &b_edge[8 * k16];
            u32 o0 = (u32)f2bf(axg0.x * inv + bes * br[0]) |
                     ((u32)f2bf(axg0.y * inv + bes * br[1]) << 16);
            u32 o1 = (u32)f2bf(axg1.x * inv + bes * br[2]) |
                     ((u32)f2bf(axg1.y * inv + bes * br[3]) << 16);
            u32 o2 = (u32)f2bf(axg2.x * inv + bes * br[4]) |
                     ((u32)f2bf(axg2.y * inv + bes * br[5]) << 16);
            u32 o3 = (u32)f2bf(axg3.x * inv + bes * br[6]) |
                     ((u32)f2bf(axg3.y * inv + bes * br[7]) << 16);
            uint4 st = {o0, o1, o2, o3};
            *(uint4*)(agg + (size_t)n * 512 + (2 * hp + hsel) * 128 + 8 * k16) = st;
        }
    }
#undef IDX8
#undef LOADP
#undef COMP
}

// ---------------- G3 (MFMA): out = relu(x + agg @ W_out + b_out) ---------------------
__global__ __launch_bounds__(256) void g3_kernel(const u16* __restrict__ Xc,
                                                 const u16* __restrict__ agg,
                                                 const u16* __restrict__ WoT,
                                                 const float* __restrict__ bout,
                                                 const int* __restrict__ avgflag,
                                                 float* __restrict__ out, int N) {
    int t = threadIdx.x;
    int r0 = blockIdx.x * 64;
    if (*avgflag) {
        for (int i = t; i < 64 * 128; i += 256) {
            int n = r0 + (i >> 7), j = i & 127;
            if (n < N) {
                float s = 0.f;
#pragma unroll
                for (int h = 0; h < 4; ++h) s += bf2f(agg[(size_t)n * 512 + h * 128 + j]);
                float v = bf2f(Xc[(size_t)n * 128 + j]) + 0.25f * s;
                out[(size_t)n * 128 + j] = v > 0.f ? v : 0.f;
            }
        }
        return;
    }
    __shared__ u16 Asm[64][72];
    __shared__ u16 Bsm[128][72];
    int lane = t & 63, wave = t >> 6;
    int wm = wave >> 1, wn = wave & 1;
    int lr = lane & 15, lk = lane >> 4;
    f4 acc[2][4] = {};
    for (int kb = 0; kb < 8; ++kb) {
        if (kb) __syncthreads();
        {
            int row = t >> 2, ks = (t & 3) * 16;
            int r = r0 + row;
            uint4 v0 = {0, 0, 0, 0}, v1 = {0, 0, 0, 0};
            if (r < N) {
                const u16* src = &agg[(size_t)r * 512 + kb * 64 + ks];
                v0 = *(const uint4*)src;
                v1 = *(const uint4*)(src + 8);
            }
            *(uint4*)&Asm[row][ks] = v0;
            *(uint4*)&Asm[row][ks + 8] = v1;
        }
        {
            int col = t >> 1, ks = (t & 1) * 32;
            const u16* src = &WoT[(size_t)col * 512 + kb * 64 + ks];
            uint4 v0 = *(const uint4*)src;
            uint4 v1 = *(const uint4*)(src + 8);
            uint4 v2 = *(const uint4*)(src + 16);
            uint4 v3 = *(const uint4*)(src + 24);
            *(uint4*)&Bsm[col][ks] = v0;
            *(uint4*)&Bsm[col][ks + 8] = v1;
            *(uint4*)&Bsm[col][ks + 16] = v2;
            *(uint4*)&Bsm[col][ks + 24] = v3;
        }
        __syncthreads();
#pragma unroll
        for (int kk = 0; kk < 2; ++kk) {
            bh8 a[2], b[4];
#pragma unroll
            for (int am = 0; am < 2; ++am)
                a[am] = *(const bh8*)&Asm[wm * 32 + am * 16 + lr][kk * 32 + lk * 8];
#pragma unroll
            for (int bn = 0; bn < 4; ++bn)
                b[bn] = *(const bh8*)&Bsm[wn * 64 + bn * 16 + lr][kk * 32 + lk * 8];
#pragma unroll
            for (int am = 0; am < 2; ++am)
#pragma unroll
                for (int bn = 0; bn < 4; ++bn)
                    acc[am][bn] = __builtin_amdgcn_mfma_f32_16x16x32_bf16(a[am], b[bn], acc[am][bn], 0, 0, 0);
        }
    }
#pragma unroll
    for (int am = 0; am < 2; ++am)
#pragma unroll
        for (int bn = 0; bn < 4; ++bn) {
            int c = wn * 64 + bn * 16 + lr;
            float bc = bout[c];
#pragma unroll
            for (int q = 0; q < 4; ++q) {
                int r = r0 + wm * 32 + am * 16 + lk * 4 + q;
                if (r < N) {
                    float v = acc[am][bn][q] + bc + bf2f(Xc[(size_t)r * 128 + c]);
                    out[(size_t)r * 128 + c] = v > 0.f ? v : 0.f;
                }
            }
        }
}

// ---------------- launch --------------------------------------------------------------
extern "C" void kernel_launch(void* const* d_in, const int* in_sizes, int n_in, void* d_out,
                              int out_size, void* d_ws, size_t ws_size, hipStream_t stream) {
    const float* nodes = (const float*)d_in[0];
    const float* edges = (const float*)d_in[1];
    const int* senders = (const int*)d_in[2];
    const int* receivers = (const int*)d_in[3];
    const int* avgflag = (const int*)d_in[4];
    const float* W_node = (const float*)d_in[5];
    const float* b_node = (const float*)d_in[6];
    const float* W_edge = (const float*)d_in[7];
    const float* b_edge = (const float*)d_in[8];
    const float* Wk_s = (const float*)d_in[9];
    const float* bk_s = (const float*)d_in[10];
    const float* Wk_r = (const float*)d_in[11];
    const float* bk_r = (const float*)d_in[12];
    const float* W_out = (const float*)d_in[13];
    const float* b_out = (const float*)d_in[14];
    int N = in_sizes[0] / 64;
    int E = in_sizes[2];
    float* outp = (float*)d_out;

    char* base = (char*)d_ws;
    size_t off = 0;
    auto alloc = [&](size_t nbytes) -> char* {
        char* p = base + off;
        off = (off + nbytes + 255) & ~(size_t)255;
        return p;
    };
    u16* Xc = (u16*)alloc((size_t)N * 128 * 2);
    u16* V = (u16*)alloc((size_t)N * 512 * 2);
    u16* U = (u16*)alloc((size_t)N * 64 * 2);
    float* E0 = (float*)alloc((size_t)N * 4 * 4);
    u16* agg = (u16*)alloc((size_t)N * 512 * 2);
    int* deg = (int*)alloc((size_t)N * 4);
    int* row_start = (int*)alloc((size_t)(N + 1) * 4);
    int* cursor = (int*)alloc((size_t)N * 4);
    int2* esp = (int2*)alloc((size_t)E * 8);
    int* pre = (int*)alloc((size_t)N * 4);
    int* bsum = (int*)alloc((size_t)128 * 4);
    int* boff = (int*)alloc((size_t)128 * 4);
    float* A = (float*)alloc((size_t)4 * 64 * 128 * 4);
    float* B = (float*)alloc((size_t)4 * 64 * 128 * 4);
    float* ybr = (float*)alloc((size_t)4 * 128 * 4);
    float* ybs = (float*)alloc((size_t)4 * 128 * 4);
    float* Wfold = (float*)alloc((size_t)64 * 708 * 4);
    float* biasrow = (float*)alloc((size_t)712 * 4);
    u16* WfT = (u16*)alloc((size_t)768 * 64 * 2);
    u16* WoT = (u16*)alloc((size_t)128 * 512 * 2);

    int nb = (N + 1023) >> 10;

    hipMemsetAsync(deg, 0, (size_t)N * 4, stream);
    k0a_kernel<<<256, 256, 0, stream>>>(W_node, Wk_s, Wk_r, A, B);
    k0a2_kernel<<<4, 256, 0, stream>>>(b_node, Wk_s, Wk_r, bk_s, bk_r, ybs, ybr);
    k0b_kernel<<<(65 * 708 + 255) / 256, 256, 0, stream>>>(W_node, b_node, A, B, ybr, ybs,
                                                           Wk_s, W_edge, bk_s, b_edge, Wfold,
                                                           biasrow);
    wconv_kernel<<<(768 * 64 + 128 * 512 + 255) / 256, 256, 0, stream>>>(Wfold, W_out, WfT, WoT);
    dim3 g1grid((N + 63) / 64, 6);
    g1_kernel<<<g1grid, 256, 0, stream>>>(nodes, WfT, biasrow, Xc, V, U, E0, N);
    hist_kernel<<<(E + 255) / 256, 256, 0, stream>>>(receivers, deg, E);
    scan1_kernel<<<nb, 1024, 0, stream>>>(deg, pre, bsum, N);
    scan2_kernel<<<1, 64, 0, stream>>>(bsum, boff, nb);
    scan3_kernel<<<(N + 1024) / 1024, 1024, 0, stream>>>(pre, boff, row_start, cursor, N);
    scatter_kernel<<<(E + 255) / 256, 256, 0, stream>>>(receivers, senders, cursor, esp, E);
    en_kernel<<<4096, 256, 0, stream>>>(row_start, esp, edges, Xc, V, U, E0, W_edge,
                                        b_edge, agg, N);
    g3_kernel<<<(N + 63) / 64, 256, 0, stream>>>(Xc, agg, WoT, b_out, avgflag, outp, N);
}

// Round 9
// 330.950 us; speedup vs baseline: 1.0595x; 1.0595x over previous
//
#include <hip/hip_runtime.h>

typedef unsigned short u16;
typedef unsigned int u32;
typedef short bh8 __attribute__((ext_vector_type(8)));   // 8 bf16 (A/B frag)
typedef float f4 __attribute__((ext_vector_type(4)));    // 4 f32 (C/D frag)
typedef float pf2 __attribute__((ext_vector_type(2)));   // packed f32 pair

__device__ __forceinline__ float bf2f(u16 h) { return __uint_as_float(((u32)h) << 16); }
__device__ __forceinline__ float bflo(u32 u) { return __uint_as_float(u << 16); }
__device__ __forceinline__ float bfhi(u32 u) { return __uint_as_float(u & 0xffff0000u); }
__device__ __forceinline__ u16 f2bf(float f) {
    u32 x = __float_as_uint(f);
    return (u16)((x + 0x7fffu + ((x >> 16) & 1u)) >> 16);  // RNE
}
__device__ __forceinline__ pf2 pkfma(pf2 a, pf2 b, pf2 c) {
    pf2 d;
    asm("v_pk_fma_f32 %0, %1, %2, %3" : "=v"(d) : "v"(a), "v"(b), "v"(c));
    return d;
}
__device__ __forceinline__ pf2 u2f2(u32 u) {
    pf2 r;
    r.x = bflo(u);
    r.y = bfhi(u);
    return r;
}
// 16-lane sum via DPP (VALU pipe, no LDS)
__device__ __forceinline__ float dpp_red16(float x) {
    int y;
    y = __builtin_amdgcn_update_dpp(0, __float_as_int(x), 0xB1, 0xF, 0xF, true);
    x += __int_as_float(y);
    y = __builtin_amdgcn_update_dpp(0, __float_as_int(x), 0x4E, 0xF, 0xF, true);
    x += __int_as_float(y);
    y = __builtin_amdgcn_update_dpp(0, __float_as_int(x), 0x141, 0xF, 0xF, true);
    x += __int_as_float(y);
    y = __builtin_amdgcn_update_dpp(0, __float_as_int(x), 0x140, 0xF, 0xF, true);
    x += __int_as_float(y);
    return x;
}

#define KSCL 0.12751744336457488f  // (1/sqrt(128)) * log2(e)

// ---------------- K0a: A_h = W_node @ Wk_r[h], B_h = W_node @ Wk_s[h] ----------------
__global__ void k0a_kernel(const float* __restrict__ Wn, const float* __restrict__ Wks,
                           const float* __restrict__ Wkr, float* __restrict__ A,
                           float* __restrict__ B) {
    int idx = blockIdx.x * 256 + threadIdx.x;  // 2*4*64*128 = 65536
    if (idx >= 65536) return;
    int which = idx >> 15;
    int rem = idx & 32767;
    int h = rem >> 13;
    int r = rem & 8191;
    int a = r >> 7, dp = r & 127;
    const float* W = which ? Wks : Wkr;
    float acc = 0.f;
    for (int d = 0; d < 128; ++d)
        acc += Wn[a * 128 + d] * W[(h * 128 + d) * 128 + dp];
    (which ? B : A)[(h * 64 + a) * 128 + dp] = acc;
}

// ---------------- K0a2 ---------------------------------------------------------------
__global__ void k0a2_kernel(const float* __restrict__ bn, const float* __restrict__ Wks,
                            const float* __restrict__ Wkr, const float* __restrict__ bks,
                            const float* __restrict__ bkr, float* __restrict__ ybs,
                            float* __restrict__ ybr) {
    int idx = blockIdx.x * 256 + threadIdx.x;  // 2*4*128 = 1024
    if (idx >= 1024) return;
    int which = idx >> 9;
    int rem = idx & 511;
    int h = rem >> 7, dp = rem & 127;
    const float* W = which ? Wks : Wkr;
    const float* b = which ? bks : bkr;
    float acc = b[h * 128 + dp];
    for (int d = 0; d < 128; ++d) acc += bn[d] * W[(h * 128 + d) * 128 + dp];
    (which ? ybs : ybr)[h * 128 + dp] = acc;
}

// ---------------- K0b: assemble Wfold [64 x 708] + biasrow[708] ----------------------
// cols: [0:128) x | [128:640) v(h,i) | [640:704) u k-major: 640+k*4+h | [704:708) c0_h
__global__ void k0b_kernel(const float* __restrict__ Wn, const float* __restrict__ bn,
                           const float* __restrict__ A, const float* __restrict__ B,
                           const float* __restrict__ ybr, const float* __restrict__ ybs,
                           const float* __restrict__ Wks, const float* __restrict__ Wedge,
                           const float* __restrict__ bks, const float* __restrict__ bedge,
                           float* __restrict__ Wfold, float* __restrict__ biasrow) {
    int idx = blockIdx.x * 256 + threadIdx.x;  // 65*708
    if (idx >= 65 * 708) return;
    int a = idx / 708, c = idx % 708;
    float val;
    if (c < 128) {
        val = (a < 64) ? Wn[a * 128 + c] : bn[c];
    } else if (c < 640) {
        int h = (c - 128) >> 7, i = (c - 128) & 127;
        const float* rv = (a < 64) ? &A[(h * 64 + a) * 128] : &ybr[h * 128];
        float s = 0.f;
        for (int d = 0; d < 128; ++d) s += rv[d] * Wks[(h * 128 + i) * 128 + d];
        val = s;
    } else if (c < 704) {
        int k = (c - 640) >> 2, h = (c - 640) & 3;
        const float* rv = (a < 64) ? &B[(h * 64 + a) * 128] : &ybs[h * 128];
        float s = 0.f;
        for (int d = 0; d < 128; ++d) s += rv[d] * Wedge[k * 128 + d];
        val = s;
    } else {
        int h = c - 704;
        const float* rv = (a < 64) ? &B[(h * 64 + a) * 128] : &ybs[h * 128];
        float s = 0.f;
        for (int d = 0; d < 128; ++d) s += rv[d] * bedge[d];
        val = s;
    }
    if (a < 64) Wfold[(size_t)a * 708 + c] = val;
    else biasrow[c] = val;
}

// ---------------- wconv: bf16 transposed copies of Wfold and W_out -------------------
__global__ void wconv_kernel(const float* __restrict__ Wfold, const float* __restrict__ Wout,
                             u16* __restrict__ WfT, u16* __restrict__ WoT) {
    int i = blockIdx.x * 256 + threadIdx.x;
    if (i < 768 * 64) {
        int c = i >> 6, k = i & 63;
        WfT[i] = f2bf(c < 708 ? Wfold[(size_t)k * 708 + c] : 0.f);
    }
    int j = i - 768 * 64;
    if (j >= 0 && j < 128 * 512) {
        int c = j >> 9, k = j & 511;
        WoT[j] = f2bf(Wout[(size_t)k * 128 + c]);
    }
}

// ---------------- G1 (MFMA): split tables Xc[N,128], V[N,512](pre-scaled), U[N,64],
//                  E0[N,4] = exp2(kscl*c0) ------------------------------------------
__global__ __launch_bounds__(256) void g1_kernel(const float* __restrict__ nodes,
                                                 const u16* __restrict__ WfT,
                                                 const float* __restrict__ biasrow,
                                                 u16* __restrict__ Xc, u16* __restrict__ V,
                                                 u16* __restrict__ U, float* __restrict__ E0,
                                                 int N) {
    __shared__ u16 Asm[64][72];
    __shared__ u16 Bsm[128][72];
    int t = threadIdx.x;
    int r0 = blockIdx.x * 64, c0 = blockIdx.y * 128;
    {
        int row = t >> 2, cb = (t & 3) * 16;
        int r = r0 + row;
        u16 pk[16];
        if (r < N) {
            const float* src = &nodes[(size_t)r * 64 + cb];
#pragma unroll
            for (int q = 0; q < 16; ++q) pk[q] = f2bf(src[q]);
        } else {
#pragma unroll
            for (int q = 0; q < 16; ++q) pk[q] = 0;
        }
        *(uint4*)&Asm[row][cb] = *(const uint4*)&pk[0];
        *(uint4*)&Asm[row][cb + 8] = *(const uint4*)&pk[8];
    }
    {
        int col = t >> 1, ks = (t & 1) * 32;
        const u16* src = &WfT[(size_t)(c0 + col) * 64 + ks];
        uint4 v0 = *(const uint4*)src;
        uint4 v1 = *(const uint4*)(src + 8);
        uint4 v2 = *(const uint4*)(src + 16);
        uint4 v3 = *(const uint4*)(src + 24);
        *(uint4*)&Bsm[col][ks] = v0;
        *(uint4*)&Bsm[col][ks + 8] = v1;
        *(uint4*)&Bsm[col][ks + 16] = v2;
        *(uint4*)&Bsm[col][ks + 24] = v3;
    }
    __syncthreads();
    int lane = t & 63, wave = t >> 6;
    int wm = wave >> 1, wn = wave & 1;
    int lr = lane & 15, lk = lane >> 4;
    f4 acc[2][4] = {};
#pragma unroll
    for (int kk = 0; kk < 2; ++kk) {
        bh8 a[2], b[4];
#pragma unroll
        for (int am = 0; am < 2; ++am)
            a[am] = *(const bh8*)&Asm[wm * 32 + am * 16 + lr][kk * 32 + lk * 8];
#pragma unroll
        for (int bn = 0; bn < 4; ++bn)
            b[bn] = *(const bh8*)&Bsm[wn * 64 + bn * 16 + lr][kk * 32 + lk * 8];
#pragma unroll
        for (int am = 0; am < 2; ++am)
#pragma unroll
            for (int bn = 0; bn < 4; ++bn)
                acc[am][bn] = __builtin_amdgcn_mfma_f32_16x16x32_bf16(a[am], b[bn], acc[am][bn], 0, 0, 0);
    }
#pragma unroll
    for (int am = 0; am < 2; ++am)
#pragma unroll
        for (int bn = 0; bn < 4; ++bn) {
            int c = c0 + wn * 64 + bn * 16 + lr;
            if (c < 708) {
                float brow = biasrow[c];
#pragma unroll
                for (int q = 0; q < 4; ++q) {
                    int r = r0 + wm * 32 + am * 16 + lk * 4 + q;
                    if (r < N) {
                        float val = acc[am][bn][q] + brow;
                        if (c < 128) Xc[(size_t)r * 128 + c] = f2bf(val);
                        else if (c < 640) V[(size_t)r * 512 + (c - 128)] = f2bf(val * KSCL);
                        else if (c < 704) U[(size_t)r * 64 + (c - 640)] = f2bf(val * KSCL);
                        else E0[(size_t)r * 4 + (c - 704)] = exp2f(val * KSCL);
                    }
                }
            }
        }
}

// ---------------- CSR build ----------------------------------------------------------
__global__ void hist_kernel(const int* __restrict__ recv, int* __restrict__ deg, int E) {
    int e = blockIdx.x * 256 + threadIdx.x;
    if (e < E) atomicAdd(&deg[recv[e]], 1);
}

__global__ __launch_bounds__(1024) void scan1_kernel(const int* __restrict__ deg,
                                                     int* __restrict__ pre,
                                                     int* __restrict__ bsum, int N) {
    __shared__ int sm[1024];
    int b = blockIdx.x, t = threadIdx.x;
    int i = b * 1024 + t;
    int v = (i < N) ? deg[i] : 0;
    sm[t] = v;
    __syncthreads();
    for (int off = 1; off < 1024; off <<= 1) {
        int u = (t >= off) ? sm[t - off] : 0;
        __syncthreads();
        sm[t] += u;
        __syncthreads();
    }
    if (i < N) pre[i] = sm[t] - v;
    if (t == 1023) bsum[b] = sm[1023];
}

__global__ void scan2_kernel(int* __restrict__ bsum, int* __restrict__ boff, int nb) {
    int t = threadIdx.x;  // 64 threads, nb <= 64
    int own = (t < nb) ? bsum[t] : 0;
    int v = own;
#pragma unroll
    for (int off = 1; off < 64; off <<= 1) {
        int u = __shfl_up(v, off);
        if (t >= off) v += u;
    }
    if (t < nb) boff[t] = v - own;
    if (t == 63) boff[64] = v;
}

__global__ void scan3_kernel(const int* __restrict__ pre, const int* __restrict__ boff,
                             int* __restrict__ row_start, int* __restrict__ cursor, int N) {
    int i = blockIdx.x * 1024 + threadIdx.x;
    if (i < N) {
        int rsv = pre[i] + boff[i >> 10];
        row_start[i] = rsv;
        cursor[i] = rsv;
    }
    if (i == N) row_start[N] = boff[64];
}

// scatter writes fused (edge, sender) pairs -> en reads both with ONE load
__global__ void scatter_kernel(const int* __restrict__ recv, const int* __restrict__ senders,
                               int* __restrict__ cursor, int2* __restrict__ esp, int E) {
    int e = blockIdx.x * 256 + threadIdx.x;
    if (e < E) {
        int s = senders[e];
        int p = atomicAdd(&cursor[recv[e]], 1);
        esp[p] = make_int2(e, s);
    }
}

// ---------------- EN v7: 4 heads/wave (single gather per edge), 8 edges/step ---------
// Wave = node. Lane = (g,k16). Group g handles edge slot 8s+g and 8s+4+g; k16 = 8 ch.
__global__ __launch_bounds__(256, 3) void en_kernel(const int* __restrict__ row_start,
                                                    const int2* __restrict__ esp,
                                                    const float* __restrict__ edges,
                                                    const u16* __restrict__ Xc,
                                                    const u16* __restrict__ V,
                                                    const u16* __restrict__ Uu,
                                                    const float* __restrict__ E0,
                                                    const float* __restrict__ W_edge,
                                                    const float* __restrict__ b_edge,
                                                    u16* __restrict__ agg, int N) {
    __shared__ float Wl[2048];  // swizzled: (k, ch=8*k16+2i+b) at k*128+32*i+2*k16+b
    int t = threadIdx.x;
    for (int i = t; i < 2048; i += 256) {
        int k = i >> 7, ch = i & 127;
        int pos = (k << 7) | ((((ch >> 1) & 3) << 5) | (((ch >> 3) & 15) << 1) | (ch & 1));
        Wl[pos] = W_edge[i];
    }
    __syncthreads();
    int lane = t & 63, wid = t >> 6;
    int g = lane >> 4, k16 = lane & 15;
    int nw = blockIdx.x * 4 + wid;
    int NW = gridDim.x * 4;

#define IDX8(ea, sa, eb, sb, s_)                                            \
    {                                                                       \
        int ev = 0, sv = 0;                                                 \
        if (lane < 8) {                                                     \
            int jj = (s_)*8 + lane;                                         \
            if (jj >= deg) jj = deg - 1;                                    \
            int2 pv = esp[rs + jj];                                         \
            ev = pv.x; sv = pv.y;                                           \
        }                                                                   \
        ea = __shfl(ev, g); sa = __shfl(sv, g);                             \
        eb = __shfl(ev, 4 + g); sb = __shfl(sv, 4 + g);                     \
    }

#define LOADP(Xq, Uq, Eq, Zq, eI, sI)                                       \
    {                                                                       \
        Xq = *(const uint4*)(Xc + (size_t)(sI)*128 + 8 * k16);              \
        Uq = *(const uint2*)(Uu + (size_t)(sI)*64 + k16 * 4);               \
        Eq = edges[(size_t)(eI)*16 + k16];                                  \
        Zq = *(const float4*)(E0 + (size_t)(sI)*4);                         \
    }

#define COMP(Xq, Uq, Eq, Zq, act)                                           \
    {                                                                       \
        pf2 X0 = u2f2(Xq.x), X1 = u2f2(Xq.y), X2 = u2f2(Xq.z), X3 = u2f2(Xq.w); \
        float uh[4] = {bflo(Uq.x), bfhi(Uq.x), bflo(Uq.y), bfhi(Uq.y)};     \
        float e0a[4] = {Zq.x, Zq.y, Zq.z, Zq.w};                            \
        _Pragma("unroll") for (int h = 0; h < 4; ++h) {                     \
            pf2 p2 = {Eq * uh[h], 0.f};                                     \
            p2 = pkfma(X0, vr[h][0], p2); p2 = pkfma(X1, vr[h][1], p2);     \
            p2 = pkfma(X2, vr[h][2], p2); p2 = pkfma(X3, vr[h][3], p2);     \
            float p = dpp_red16(p2.x + p2.y);                               \
            float wh = (act) ? e0a[h] * exp2f(p) : 0.f;                     \
            Ss[h] += wh; aE[h] = fmaf(wh, Eq, aE[h]);                       \
            pf2 w2 = {wh, wh};                                              \
            aX[h][0] = pkfma(w2, X0, aX[h][0]);                             \
            aX[h][1] = pkfma(w2, X1, aX[h][1]);                             \
            aX[h][2] = pkfma(w2, X2, aX[h][2]);                             \
            aX[h][3] = pkfma(w2, X3, aX[h][3]);                             \
        }                                                                   \
    }

    for (int n = nw; n < N; n += NW) {
        int rs = row_start[n];
        int deg = row_start[n + 1] - rs;
        const u16* Vr = V + (size_t)n * 512;
        pf2 vr[4][4];
#pragma unroll
        for (int h = 0; h < 4; ++h) {
            uint4 v = *(const uint4*)(Vr + h * 128 + 8 * k16);
            vr[h][0] = u2f2(v.x); vr[h][1] = u2f2(v.y);
            vr[h][2] = u2f2(v.z); vr[h][3] = u2f2(v.w);
        }
        pf2 aX[4][4] = {};
        float Ss[4] = {0.f, 0.f, 0.f, 0.f};
        float aE[4] = {0.f, 0.f, 0.f, 0.f};

        if (deg > 0) {
            int nst = (deg + 7) >> 3;
            int eA0, sA0, eA1, sA1, eB0, sB0, eB1, sB1;
            IDX8(eA0, sA0, eA1, sA1, 0);
            uint4 xP0, xP1; uint2 uP0, uP1; float eP0, eP1; float4 zP0, zP1;
            LOADP(xP0, uP0, eP0, zP0, eA0, sA0);
            LOADP(xP1, uP1, eP1, zP1, eA1, sA1);
            if (nst > 1) {
                IDX8(eB0, sB0, eB1, sB1, 1);
            } else {
                eB0 = eA0; sB0 = sA0; eB1 = eA1; sB1 = sA1;
            }
            for (int s = 0; s < nst; ++s) {
                uint4 xc0 = xP0, xc1 = xP1;
                uint2 uc0 = uP0, uc1 = uP1;
                float ec0 = eP0, ec1 = eP1;
                float4 zc0 = zP0, zc1 = zP1;
                int base = s * 8;
                if (s + 1 < nst) {
                    LOADP(xP0, uP0, eP0, zP0, eB0, sB0);
                    LOADP(xP1, uP1, eP1, zP1, eB1, sB1);
                    if (s + 2 < nst) IDX8(eB0, sB0, eB1, sB1, s + 2);
                }
                COMP(xc0, uc0, ec0, zc0, base + g < deg);
                COMP(xc1, uc1, ec1, zc1, base + 4 + g < deg);
            }
        }
        // cross-group reduce (sum over the 4 edge-groups)
#pragma unroll
        for (int h = 0; h < 4; ++h) {
#pragma unroll
            for (int i = 0; i < 4; ++i) {
                pf2 v = aX[h][i];
                v.x += __shfl_xor(v.x, 16); v.y += __shfl_xor(v.y, 16);
                v.x += __shfl_xor(v.x, 32); v.y += __shfl_xor(v.y, 32);
                aX[h][i] = v;
            }
            Ss[h] += __shfl_xor(Ss[h], 16); Ss[h] += __shfl_xor(Ss[h], 32);
            aE[h] += __shfl_xor(aE[h], 16); aE[h] += __shfl_xor(aE[h], 32);
        }
        // finalize: group g owns head g over the full k range
        pf2 axg[4];
#pragma unroll
        for (int i = 0; i < 4; ++i)
            axg[i] = g == 0 ? aX[0][i] : g == 1 ? aX[1][i] : g == 2 ? aX[2][i] : aX[3][i];
        float aEg = g == 0 ? aE[0] : g == 1 ? aE[1] : g == 2 ? aE[2] : aE[3];
        float Sg = g == 0 ? Ss[0] : g == 1 ? Ss[1] : g == 2 ? Ss[2] : Ss[3];
        const pf2* Wp = (const pf2*)Wl;
#pragma unroll
        for (int kk = 0; kk < 16; ++kk) {
            float a = __shfl(aEg, (g << 4) | kk);  // broadcast within own group
            pf2 a2 = {a, a};
            int base = (kk << 6) + k16;  // same addr across groups -> LDS broadcast
            axg[0] = pkfma(a2, Wp[base], axg[0]);
            axg[1] = pkfma(a2, Wp[base + 16], axg[1]);
            axg[2] = pkfma(a2, Wp[base + 32], axg[2]);
            axg[3] = pkfma(a2, Wp[base + 48], axg[3]);
        }
        {
            float inv = (deg > 0 && Sg > 0.f) ? 1.f / Sg : 0.f;
            float bes = (deg > 0) ? 1.f : 0.f;
            const float* br = &b_edge[8 * k16];
            u32 o0 = (u32)f2bf(axg[0].x * inv + bes * br[0]) |
                     ((u32)f2bf(axg[0].y * inv + bes * br[1]) << 16);
            u32 o1 = (u32)f2bf(axg[1].x * inv + bes * br[2]) |
                     ((u32)f2bf(axg[1].y * inv + bes * br[3]) << 16);
            u32 o2 = (u32)f2bf(axg[2].x * inv + bes * br[4]) |
                     ((u32)f2bf(axg[2].y * inv + bes * br[5]) << 16);
            u32 o3 = (u32)f2bf(axg[3].x * inv + bes * br[6]) |
                     ((u32)f2bf(axg[3].y * inv + bes * br[7]) << 16);
            uint4 st = {o0, o1, o2, o3};
            *(uint4*)(agg + (size_t)n * 512 + g * 128 + 8 * k16) = st;
        }
    }
#undef IDX8
#undef LOADP
#undef COMP
}

// ---------------- G3 (MFMA): out = relu(x + agg @ W_out + b_out) ---------------------
__global__ __launch_bounds__(256) void g3_kernel(const u16* __restrict__ Xc,
                                                 const u16* __restrict__ agg,
                                                 const u16* __restrict__ WoT,
                                                 const float* __restrict__ bout,
                                                 const int* __restrict__ avgflag,
                                                 float* __restrict__ out, int N) {
    int t = threadIdx.x;
    int r0 = blockIdx.x * 64;
    if (*avgflag) {
        for (int i = t; i < 64 * 128; i += 256) {
            int n = r0 + (i >> 7), j = i & 127;
            if (n < N) {
                float s = 0.f;
#pragma unroll
                for (int h = 0; h < 4; ++h) s += bf2f(agg[(size_t)n * 512 + h * 128 + j]);
                float v = bf2f(Xc[(size_t)n * 128 + j]) + 0.25f * s;
                out[(size_t)n * 128 + j] = v > 0.f ? v : 0.f;
            }
        }
        return;
    }
    __shared__ u16 Asm[64][72];
    __shared__ u16 Bsm[128][72];
    int lane = t & 63, wave = t >> 6;
    int wm = wave >> 1, wn = wave & 1;
    int lr = lane & 15, lk = lane >> 4;
    f4 acc[2][4] = {};
    for (int kb = 0; kb < 8; ++kb) {
        if (kb) __syncthreads();
        {
            int row = t >> 2, ks = (t & 3) * 16;
            int r = r0 + row;
            uint4 v0 = {0, 0, 0, 0}, v1 = {0, 0, 0, 0};
            if (r < N) {
                const u16* src = &agg[(size_t)r * 512 + kb * 64 + ks];
                v0 = *(const uint4*)src;
                v1 = *(const uint4*)(src + 8);
            }
            *(uint4*)&Asm[row][ks] = v0;
            *(uint4*)&Asm[row][ks + 8] = v1;
        }
        {
            int col = t >> 1, ks = (t & 1) * 32;
            const u16* src = &WoT[(size_t)col * 512 + kb * 64 + ks];
            uint4 v0 = *(const uint4*)src;
            uint4 v1 = *(const uint4*)(src + 8);
            uint4 v2 = *(const uint4*)(src + 16);
            uint4 v3 = *(const uint4*)(src + 24);
            *(uint4*)&Bsm[col][ks] = v0;
            *(uint4*)&Bsm[col][ks + 8] = v1;
            *(uint4*)&Bsm[col][ks + 16] = v2;
            *(uint4*)&Bsm[col][ks + 24] = v3;
        }
        __syncthreads();
#pragma unroll
        for (int kk = 0; kk < 2; ++kk) {
            bh8 a[2], b[4];
#pragma unroll
            for (int am = 0; am < 2; ++am)
                a[am] = *(const bh8*)&Asm[wm * 32 + am * 16 + lr][kk * 32 + lk * 8];
#pragma unroll
            for (int bn = 0; bn < 4; ++bn)
                b[bn] = *(const bh8*)&Bsm[wn * 64 + bn * 16 + lr][kk * 32 + lk * 8];
#pragma unroll
            for (int am = 0; am < 2; ++am)
#pragma unroll
                for (int bn = 0; bn < 4; ++bn)
                    acc[am][bn] = __builtin_amdgcn_mfma_f32_16x16x32_bf16(a[am], b[bn], acc[am][bn], 0, 0, 0);
        }
    }
#pragma unroll
    for (int am = 0; am < 2; ++am)
#pragma unroll
        for (int bn = 0; bn < 4; ++bn) {
            int c = wn * 64 + bn * 16 + lr;
            float bc = bout[c];
#pragma unroll
            for (int q = 0; q < 4; ++q) {
                int r = r0 + wm * 32 + am * 16 + lk * 4 + q;
                if (r < N) {
                    float v = acc[am][bn][q] + bc + bf2f(Xc[(size_t)r * 128 + c]);
                    out[(size_t)r * 128 + c] = v > 0.f ? v : 0.f;
                }
            }
        }
}

// ---------------- launch --------------------------------------------------------------
extern "C" void kernel_launch(void* const* d_in, const int* in_sizes, int n_in, void* d_out,
                              int out_size, void* d_ws, size_t ws_size, hipStream_t stream) {
    const float* nodes = (const float*)d_in[0];
    const float* edges = (const float*)d_in[1];
    const int* senders = (const int*)d_in[2];
    const int* receivers = (const int*)d_in[3];
    const int* avgflag = (const int*)d_in[4];
    const float* W_node = (const float*)d_in[5];
    const float* b_node = (const float*)d_in[6];
    const float* W_edge = (const float*)d_in[7];
    const float* b_edge = (const float*)d_in[8];
    const float* Wk_s = (const float*)d_in[9];
    const float* bk_s = (const float*)d_in[10];
    const float* Wk_r = (const float*)d_in[11];
    const float* bk_r = (const float*)d_in[12];
    const float* W_out = (const float*)d_in[13];
    const float* b_out = (const float*)d_in[14];
    int N = in_sizes[0] / 64;
    int E = in_sizes[2];
    float* outp = (float*)d_out;

    char* base = (char*)d_ws;
    size_t off = 0;
    auto alloc = [&](size_t nbytes) -> char* {
        char* p = base + off;
        off = (off + nbytes + 255) & ~(size_t)255;
        return p;
    };
    u16* Xc = (u16*)alloc((size_t)N * 128 * 2);
    u16* V = (u16*)alloc((size_t)N * 512 * 2);
    u16* U = (u16*)alloc((size_t)N * 64 * 2);
    float* E0 = (float*)alloc((size_t)N * 4 * 4);
    u16* agg = (u16*)alloc((size_t)N * 512 * 2);
    int* deg = (int*)alloc((size_t)N * 4);
    int* row_start = (int*)alloc((size_t)(N + 1) * 4);
    int* cursor = (int*)alloc((size_t)N * 4);
    int2* esp = (int2*)alloc((size_t)E * 8);
    int* pre = (int*)alloc((size_t)N * 4);
    int* bsum = (int*)alloc((size_t)128 * 4);
    int* boff = (int*)alloc((size_t)128 * 4);
    float* A = (float*)alloc((size_t)4 * 64 * 128 * 4);
    float* B = (float*)alloc((size_t)4 * 64 * 128 * 4);
    float* ybr = (float*)alloc((size_t)4 * 128 * 4);
    float* ybs = (float*)alloc((size_t)4 * 128 * 4);
    float* Wfold = (float*)alloc((size_t)64 * 708 * 4);
    float* biasrow = (float*)alloc((size_t)712 * 4);
    u16* WfT = (u16*)alloc((size_t)768 * 64 * 2);
    u16* WoT = (u16*)alloc((size_t)128 * 512 * 2);

    int nb = (N + 1023) >> 10;

    hipMemsetAsync(deg, 0, (size_t)N * 4, stream);
    k0a_kernel<<<256, 256, 0, stream>>>(W_node, Wk_s, Wk_r, A, B);
    k0a2_kernel<<<4, 256, 0, stream>>>(b_node, Wk_s, Wk_r, bk_s, bk_r, ybs, ybr);
    k0b_kernel<<<(65 * 708 + 255) / 256, 256, 0, stream>>>(W_node, b_node, A, B, ybr, ybs,
                                                           Wk_s, W_edge, bk_s, b_edge, Wfold,
                                                           biasrow);
    wconv_kernel<<<(768 * 64 + 128 * 512 + 255) / 256, 256, 0, stream>>>(Wfold, W_out, WfT, WoT);
    dim3 g1grid((N + 63) / 64, 6);
    g1_kernel<<<g1grid, 256, 0, stream>>>(nodes, WfT, biasrow, Xc, V, U, E0, N);
    hist_kernel<<<(E + 255) / 256, 256, 0, stream>>>(receivers, deg, E);
    scan1_kernel<<<nb, 1024, 0, stream>>>(deg, pre, bsum, N);
    scan2_kernel<<<1, 64, 0, stream>>>(bsum, boff, nb);
    scan3_kernel<<<(N + 1024) / 1024, 1024, 0, stream>>>(pre, boff, row_start, cursor, N);
    scatter_kernel<<<(E + 255) / 256, 256, 0, stream>>>(receivers, senders, cursor, esp, E);
    en_kernel<<<4096, 256, 0, stream>>>(row_start, esp, edges, Xc, V, U, E0, W_edge,
                                        b_edge, agg, N);
    g3_kernel<<<(N + 63) / 64, 256, 0, stream>>>(Xc, agg, WoT, b_out, avgflag, outp, N);
}